// Round 5
// baseline (112.109 us; speedup 1.0000x reference)
//
#include <hip/hip_runtime.h>
#include <hip/hip_bf16.h>
#include <hip/hip_fp16.h>

// Self-attention: B=4, N=4096 (64x64 spatial), C=256, D=32.
//   proj_kernel : q,k,v = x@W{q,k,v}+b -> f16. q (pre-scaled by log2e), k row-major
//                 [B*N][32]; v transposed [B][32][N].
//   attn_kernel : block = 16 q-rows, 8 waves k-split (512 k each) flash attention,
//                 swapped-operand MFMA (S^T = K*Q^T, feat^T = V^T*P^T).
//                 Software-pipelined: V loads issued before the softmax branch,
//                 next iteration's K fragments prefetched at top of body.

#define BB 4
#define NN 4096
#define CC 256
#define DD 32
#define LOG2E 1.44269504088896340736f
#define THR2 11.0f

typedef _Float16 half_t;
typedef _Float16 half2_t __attribute__((ext_vector_type(2)));
typedef _Float16 half4_t __attribute__((ext_vector_type(4)));
typedef _Float16 half8_t __attribute__((ext_vector_type(8)));
typedef float f32x4 __attribute__((ext_vector_type(4)));

#define MFMA_QK(a, b, c) __builtin_amdgcn_mfma_f32_16x16x32_f16(a, b, c, 0, 0, 0)
#define MFMA_PV(a, b, c) __builtin_amdgcn_mfma_f32_16x16x16f16(a, b, c, 0, 0, 0)

static __device__ inline float fexp2(float x) {
#if __has_builtin(__builtin_amdgcn_exp2f)
    return __builtin_amdgcn_exp2f(x);
#else
    return exp2f(x);
#endif
}

// ---------------- Kernel 1: fused QKV projection ----------------
// grid 1024 blocks x 192 threads; block = 16 rows of x.
__global__ __launch_bounds__(192) void proj_kernel(
    const float* __restrict__ x,
    const float* __restrict__ Wk, const float* __restrict__ bk,
    const float* __restrict__ Wq, const float* __restrict__ bq,
    const float* __restrict__ Wv, const float* __restrict__ bv,
    half_t* __restrict__ k_ws, half_t* __restrict__ q_ws, half_t* __restrict__ vT_ws)
{
    __shared__ float xs[16 * 264];
    const int t = threadIdx.x;
    const int row0 = blockIdx.x * 16;

    const float4* x4 = reinterpret_cast<const float4*>(x) + (size_t)row0 * 64;
    for (int idx = t; idx < 16 * 64; idx += 192) {
        int r = idx >> 6, c4 = idx & 63;
        *reinterpret_cast<float4*>(&xs[r * 264 + c4 * 4]) = x4[r * 64 + c4];
    }
    __syncthreads();

    const int og = t % 24;        // 4 channels of fused 96
    const int rg = t / 24;        // 0..7 -> rows rg*2, rg*2+1
    const int mat = og >> 3;      // 0:k 1:q 2:v
    const int ol = (og & 7) * 4;
    const float* Wm = (mat == 0) ? Wk : ((mat == 1) ? Wq : Wv);
    const float* bm = (mat == 0) ? bk : ((mat == 1) ? bq : bv);

    float a00 = 0.f, a01 = 0.f, a10 = 0.f, a11 = 0.f,
          a20 = 0.f, a21 = 0.f, a30 = 0.f, a31 = 0.f;
    const float* xr = &xs[rg * 2 * 264];
#pragma unroll 8
    for (int c = 0; c < 256; ++c) {
        float4 w4 = *reinterpret_cast<const float4*>(Wm + c * DD + ol);
        float x0 = xr[c], x1 = xr[264 + c];
        a00 += x0 * w4.x; a01 += x1 * w4.x;
        a10 += x0 * w4.y; a11 += x1 * w4.y;
        a20 += x0 * w4.z; a21 += x1 * w4.z;
        a30 += x0 * w4.w; a31 += x1 * w4.w;
    }
    float b0 = bm[ol], b1 = bm[ol + 1], b2 = bm[ol + 2], b3 = bm[ol + 3];
    const float scl = (mat == 1) ? LOG2E : 1.0f;  // q pre-scaled: softmax in log2 domain

    if (mat < 2) {
        half_t* dst = (mat == 0) ? k_ws : q_ws;
        int row = row0 + rg * 2;
        half4_t h0, h1;
        h0[0] = (half_t)((a00 + b0) * scl); h1[0] = (half_t)((a01 + b0) * scl);
        h0[1] = (half_t)((a10 + b1) * scl); h1[1] = (half_t)((a11 + b1) * scl);
        h0[2] = (half_t)((a20 + b2) * scl); h1[2] = (half_t)((a21 + b2) * scl);
        h0[3] = (half_t)((a30 + b3) * scl); h1[3] = (half_t)((a31 + b3) * scl);
        *reinterpret_cast<half4_t*>(dst + (size_t)row * DD + ol) = h0;
        *reinterpret_cast<half4_t*>(dst + (size_t)(row + 1) * DD + ol) = h1;
    } else {
        // vT[b][d][n]
        const int b = row0 >> 12;
        const int n0 = (row0 & (NN - 1)) + rg * 2;
        float ar[4][2] = {{a00, a01}, {a10, a11}, {a20, a21}, {a30, a31}};
        float bb[4] = {b0, b1, b2, b3};
#pragma unroll
        for (int oo = 0; oo < 4; ++oo) {
            half2_t h;
            h[0] = (half_t)(ar[oo][0] + bb[oo]);
            h[1] = (half_t)(ar[oo][1] + bb[oo]);
            *reinterpret_cast<half2_t*>(vT_ws + (size_t)(b * DD + ol + oo) * NN + n0) = h;
        }
    }
}

// ---------------- Kernel 2: flash attention + output projection ----------------
// grid 1024 blocks (b*256+qt) x 512 threads (8 waves). Block = 16 q rows.
// Wave w: k in [w*512, (w+1)*512), 2 tiles of 16 per iteration, 16 iterations.
__global__ __launch_bounds__(512) void attn_kernel(
    const half_t* __restrict__ k_ws, const half_t* __restrict__ q_ws,
    const half_t* __restrict__ vT_ws,
    const float* __restrict__ x, const float* __restrict__ Wo,
    const float* __restrict__ bo, const float* __restrict__ gamma,
    float* __restrict__ out)
{
    __shared__ float m_l[8][16];
    __shared__ float s_l[8][16];
    __shared__ float acc_l[8][64][8];
    __shared__ float feat_lds[16][32];

    const int tid = threadIdx.x;
    const int w = tid >> 6, lane = tid & 63;
    const int q = lane & 15, g = lane >> 4;
    const int b = blockIdx.x >> 8, qt = blockIdx.x & 255;
    const int qrow = b * NN + qt * 16 + q;

    // Q fragment (B-operand of S^T = K*Q^T): Q[qrow][8g..8g+7], pre-scaled by log2e
    half8_t qf = *reinterpret_cast<const half8_t*>(q_ws + (size_t)qrow * DD + g * 8);

    float m = -3.0e38f, ssum = 0.f;
    f32x4 accd0 = {0.f, 0.f, 0.f, 0.f};   // feat^T, d = 4g+i
    f32x4 accd1 = {0.f, 0.f, 0.f, 0.f};   // feat^T, d = 16+4g+i

    const half_t* kbase = k_ws + ((size_t)b * NN + q) * DD + g * 8;
    const half_t* vb0 = vT_ws + ((size_t)b * DD + q) * NN + g * 4;
    const half_t* vb1 = vT_ws + ((size_t)b * DD + 16 + q) * NN + g * 4;

    const int ktbase = w * 32;

    // prologue: load first iteration's K fragments
    half8_t kc0 = *reinterpret_cast<const half8_t*>(kbase + (size_t)(ktbase + 0) * 16 * DD);
    half8_t kc1 = *reinterpret_cast<const half8_t*>(kbase + (size_t)(ktbase + 1) * 16 * DD);

    for (int it = 0; it < 16; ++it) {
        const int kt = ktbase + it * 2;

        // issue V loads for this iteration NOW (consumed after the softmax chain)
        const half_t* vp0 = vb0 + (size_t)kt * 16;
        const half_t* vp1 = vb1 + (size_t)kt * 16;
        half4_t va0 = *reinterpret_cast<const half4_t*>(vp0);        // tile0, d=4g+i
        half4_t va1 = *reinterpret_cast<const half4_t*>(vp1);        // tile0, d=16+4g+i
        half4_t vc0 = *reinterpret_cast<const half4_t*>(vp0 + 16);   // tile1
        half4_t vc1 = *reinterpret_cast<const half4_t*>(vp1 + 16);

        // prefetch next iteration's K fragments (clamped on the last iter)
        const int ktn = (it < 15) ? (kt + 2) : kt;
        half8_t kn0 = *reinterpret_cast<const half8_t*>(kbase + (size_t)(ktn + 0) * 16 * DD);
        half8_t kn1 = *reinterpret_cast<const half8_t*>(kbase + (size_t)(ktn + 1) * 16 * DD);

        // QK^T on current (already-resident) K fragments
        f32x4 z = {0.f, 0.f, 0.f, 0.f};
        f32x4 s0 = MFMA_QK(kc0, qf, z);
        f32x4 s1 = MFMA_QK(kc1, qf, z);

        float t0 = fmaxf(fmaxf(s0[0], s0[1]), fmaxf(s0[2], s0[3]));
        float t1 = fmaxf(fmaxf(s1[0], s1[1]), fmaxf(s1[2], s1[3]));
        float tmax = fmaxf(t0, t1);

        // defer-max: rescale only when some lane exceeds headroom (wave-uniform branch)
        if (!__all(tmax <= m + THR2)) {
            float rmax = tmax;
            rmax = fmaxf(rmax, __shfl_xor(rmax, 16));
            rmax = fmaxf(rmax, __shfl_xor(rmax, 32));
            float mn = fmaxf(m, rmax);
            float sc = fexp2(m - mn);
            ssum *= sc;
            accd0 *= sc;
            accd1 *= sc;
            m = mn;
        }

        // softmax (log2 domain; q was pre-scaled by log2e)
        float p00 = fexp2(s0[0] - m), p01 = fexp2(s0[1] - m);
        float p02 = fexp2(s0[2] - m), p03 = fexp2(s0[3] - m);
        float p10 = fexp2(s1[0] - m), p11 = fexp2(s1[1] - m);
        float p12 = fexp2(s1[2] - m), p13 = fexp2(s1[3] - m);
        ssum += ((p00 + p01) + (p02 + p03)) + ((p10 + p11) + (p12 + p13));

        half4_t pf0, pf1;
        pf0[0] = (half_t)p00; pf0[1] = (half_t)p01; pf0[2] = (half_t)p02; pf0[3] = (half_t)p03;
        pf1[0] = (half_t)p10; pf1[1] = (half_t)p11; pf1[2] = (half_t)p12; pf1[3] = (half_t)p13;

        accd0 = MFMA_PV(va0, pf0, accd0);
        accd1 = MFMA_PV(va1, pf0, accd1);
        accd0 = MFMA_PV(vc0, pf1, accd0);
        accd1 = MFMA_PV(vc1, pf1, accd1);

        kc0 = kn0;
        kc1 = kn1;
    }

    // fold lane-local ssum to row sum (once)
    ssum += __shfl_xor(ssum, 16);
    ssum += __shfl_xor(ssum, 32);

    if (lane < 16) { m_l[w][lane] = m; s_l[w][lane] = ssum; }
#pragma unroll
    for (int i = 0; i < 4; ++i) {
        acc_l[w][lane][i] = accd0[i];
        acc_l[w][lane][4 + i] = accd1[i];
    }
    __syncthreads();

    // wave 0 combines the 8 k-splits
    if (w == 0) {
        float M = m_l[0][q];
#pragma unroll
        for (int ww = 1; ww < 8; ++ww) M = fmaxf(M, m_l[ww][q]);
        float SS = 0.f;
        float f[8] = {0.f, 0.f, 0.f, 0.f, 0.f, 0.f, 0.f, 0.f};
#pragma unroll
        for (int ww = 0; ww < 8; ++ww) {
            float sc = fexp2(m_l[ww][q] - M);
            SS += s_l[ww][q] * sc;
#pragma unroll
            for (int i = 0; i < 8; ++i) f[i] += acc_l[ww][lane][i] * sc;
        }
        float inv = 1.0f / SS;
#pragma unroll
        for (int i = 0; i < 4; ++i) {
            feat_lds[q][g * 4 + i] = f[i] * inv;
            feat_lds[q][16 + g * 4 + i] = f[4 + i] * inv;
        }
    }
    __syncthreads();

    // epilogue: 512 threads; c = tid&255, rh = tid>>8 -> 8 rows each
    const int c = tid & 255, rh = tid >> 8;
    float oacc[8];
#pragma unroll
    for (int r = 0; r < 8; ++r) oacc[r] = 0.f;
#pragma unroll 8
    for (int d = 0; d < DD; ++d) {
        float wv = Wo[d * CC + c];
#pragma unroll
        for (int r = 0; r < 8; ++r) oacc[r] += feat_lds[rh * 8 + r][d] * wv;
    }
    const float gam = gamma[0];
    const float bias = bo[c];
    const size_t base = ((size_t)b * NN + (size_t)qt * 16 + rh * 8) * CC + c;
    const float* xr = x + base;
    float* outr = out + base;
#pragma unroll
    for (int r = 0; r < 8; ++r)
        outr[(size_t)r * CC] = gam * (oacc[r] + bias) + xr[(size_t)r * CC];
}

// ---------------- launch ----------------
extern "C" void kernel_launch(void* const* d_in, const int* in_sizes, int n_in,
                              void* d_out, int out_size, void* d_ws, size_t ws_size,
                              hipStream_t stream) {
    const float* x  = (const float*)d_in[0];
    const float* Wk = (const float*)d_in[1];
    const float* bk = (const float*)d_in[2];
    const float* Wq = (const float*)d_in[3];
    const float* bq = (const float*)d_in[4];
    const float* Wv = (const float*)d_in[5];
    const float* bv = (const float*)d_in[6];
    const float* Wo = (const float*)d_in[7];
    const float* bo = (const float*)d_in[8];
    const float* gamma = (const float*)d_in[9];
    float* out = (float*)d_out;

    half_t* k_ws  = (half_t*)d_ws;
    half_t* q_ws  = k_ws + (size_t)BB * NN * DD;
    half_t* vT_ws = q_ws + (size_t)BB * NN * DD;

    proj_kernel<<<1024, 192, 0, stream>>>(x, Wk, bk, Wq, bq, Wv, bv, k_ws, q_ws, vT_ws);
    attn_kernel<<<1024, 512, 0, stream>>>(k_ws, q_ws, vT_ws, x, Wo, bo, gamma, out);
}

// Round 6
// 64.197 us; speedup vs baseline: 1.7463x; 1.7463x over previous
//
#include <hip/hip_runtime.h>
#include <hip/hip_bf16.h>
#include <hip/hip_fp16.h>

// Self-attention: B=4, N=4096 (64x64 spatial), C=256, D=32.
//   proj_kernel : q,k,v = x@W{q,k,v}+b -> f16. q (pre-scaled by log2e), k row-major
//                 [B*N][32]; v transposed [B][32][N].
//   attn_kernel : block = 64 q-rows (4 q-tiles per wave, register-resident),
//                 8 waves k-split (512 k each). Swapped-operand MFMA
//                 (S^T = K*Q^T, feat^T = V^T*P^T). Each K/V fragment load is
//                 amortized over 4 q-tiles -> 4x less L2 traffic than QBLK=16.

#define BB 4
#define NN 4096
#define CC 256
#define DD 32
#define LOG2E 1.44269504088896340736f
#define THR2 11.0f

typedef _Float16 half_t;
typedef _Float16 half2_t __attribute__((ext_vector_type(2)));
typedef _Float16 half4_t __attribute__((ext_vector_type(4)));
typedef _Float16 half8_t __attribute__((ext_vector_type(8)));
typedef float f32x4 __attribute__((ext_vector_type(4)));

#define MFMA_QK(a, b, c) __builtin_amdgcn_mfma_f32_16x16x32_f16(a, b, c, 0, 0, 0)
#define MFMA_PV(a, b, c) __builtin_amdgcn_mfma_f32_16x16x16f16(a, b, c, 0, 0, 0)

static __device__ inline float fexp2(float x) {
#if __has_builtin(__builtin_amdgcn_exp2f)
    return __builtin_amdgcn_exp2f(x);
#else
    return exp2f(x);
#endif
}

// ---------------- Kernel 1: fused QKV projection ----------------
// grid 1024 blocks x 192 threads; block = 16 rows of x.
__global__ __launch_bounds__(192) void proj_kernel(
    const float* __restrict__ x,
    const float* __restrict__ Wk, const float* __restrict__ bk,
    const float* __restrict__ Wq, const float* __restrict__ bq,
    const float* __restrict__ Wv, const float* __restrict__ bv,
    half_t* __restrict__ k_ws, half_t* __restrict__ q_ws, half_t* __restrict__ vT_ws)
{
    __shared__ float xs[16 * 264];
    const int t = threadIdx.x;
    const int row0 = blockIdx.x * 16;

    const float4* x4 = reinterpret_cast<const float4*>(x) + (size_t)row0 * 64;
    for (int idx = t; idx < 16 * 64; idx += 192) {
        int r = idx >> 6, c4 = idx & 63;
        *reinterpret_cast<float4*>(&xs[r * 264 + c4 * 4]) = x4[r * 64 + c4];
    }
    __syncthreads();

    const int og = t % 24;        // 4 channels of fused 96
    const int rg = t / 24;        // 0..7 -> rows rg*2, rg*2+1
    const int mat = og >> 3;      // 0:k 1:q 2:v
    const int ol = (og & 7) * 4;
    const float* Wm = (mat == 0) ? Wk : ((mat == 1) ? Wq : Wv);
    const float* bm = (mat == 0) ? bk : ((mat == 1) ? bq : bv);

    float a00 = 0.f, a01 = 0.f, a10 = 0.f, a11 = 0.f,
          a20 = 0.f, a21 = 0.f, a30 = 0.f, a31 = 0.f;
    const float* xr = &xs[rg * 2 * 264];
#pragma unroll 8
    for (int c = 0; c < 256; ++c) {
        float4 w4 = *reinterpret_cast<const float4*>(Wm + c * DD + ol);
        float x0 = xr[c], x1 = xr[264 + c];
        a00 += x0 * w4.x; a01 += x1 * w4.x;
        a10 += x0 * w4.y; a11 += x1 * w4.y;
        a20 += x0 * w4.z; a21 += x1 * w4.z;
        a30 += x0 * w4.w; a31 += x1 * w4.w;
    }
    float b0 = bm[ol], b1 = bm[ol + 1], b2 = bm[ol + 2], b3 = bm[ol + 3];
    const float scl = (mat == 1) ? LOG2E : 1.0f;  // q pre-scaled: softmax in log2 domain

    if (mat < 2) {
        half_t* dst = (mat == 0) ? k_ws : q_ws;
        int row = row0 + rg * 2;
        half4_t h0, h1;
        h0[0] = (half_t)((a00 + b0) * scl); h1[0] = (half_t)((a01 + b0) * scl);
        h0[1] = (half_t)((a10 + b1) * scl); h1[1] = (half_t)((a11 + b1) * scl);
        h0[2] = (half_t)((a20 + b2) * scl); h1[2] = (half_t)((a21 + b2) * scl);
        h0[3] = (half_t)((a30 + b3) * scl); h1[3] = (half_t)((a31 + b3) * scl);
        *reinterpret_cast<half4_t*>(dst + (size_t)row * DD + ol) = h0;
        *reinterpret_cast<half4_t*>(dst + (size_t)(row + 1) * DD + ol) = h1;
    } else {
        // vT[b][d][n]
        const int b = row0 >> 12;
        const int n0 = (row0 & (NN - 1)) + rg * 2;
        float ar[4][2] = {{a00, a01}, {a10, a11}, {a20, a21}, {a30, a31}};
        float bb[4] = {b0, b1, b2, b3};
#pragma unroll
        for (int oo = 0; oo < 4; ++oo) {
            half2_t h;
            h[0] = (half_t)(ar[oo][0] + bb[oo]);
            h[1] = (half_t)(ar[oo][1] + bb[oo]);
            *reinterpret_cast<half2_t*>(vT_ws + (size_t)(b * DD + ol + oo) * NN + n0) = h;
        }
    }
}

// ---------------- Kernel 2: flash attention + output projection ----------------
// grid 256 blocks (b*64+qb) x 512 threads (8 waves). Block = 64 q rows (4 tiles).
// Wave w: k in [w*512, (w+1)*512), 2 k-tiles of 16 per iteration, 16 iterations.
// Each wave computes 4 q-tiles against its k-slice; K/V fragments loaded once
// per iteration serve all 4 q-tiles.
__global__ __launch_bounds__(512) void attn_kernel(
    const half_t* __restrict__ k_ws, const half_t* __restrict__ q_ws,
    const half_t* __restrict__ vT_ws,
    const float* __restrict__ x, const float* __restrict__ Wo,
    const float* __restrict__ bo, const float* __restrict__ gamma,
    float* __restrict__ out)
{
    __shared__ float m_l[8][4][16];
    __shared__ float s_l[8][4][16];
    __shared__ float acc_l[8][64][4][8];   // 64 KB
    __shared__ float feat_lds[64][32];     // 8 KB

    const int tid = threadIdx.x;
    const int w = tid >> 6, lane = tid & 63;
    const int q = lane & 15, g = lane >> 4;
    const int b = blockIdx.x >> 6, qb = blockIdx.x & 63;
    const int q0 = qb * 64;

    // Q fragments (B-operand of S^T = K*Q^T): Q[b, q0 + t*16 + q][8g..8g+7]
    half8_t qf[4];
#pragma unroll
    for (int t = 0; t < 4; ++t)
        qf[t] = *reinterpret_cast<const half8_t*>(
            q_ws + (size_t)(b * NN + q0 + t * 16 + q) * DD + g * 8);

    float m[4], ssum[4];
    f32x4 accd0[4], accd1[4];
#pragma unroll
    for (int t = 0; t < 4; ++t) {
        m[t] = -3.0e38f; ssum[t] = 0.f;
        accd0[t] = (f32x4){0.f, 0.f, 0.f, 0.f};
        accd1[t] = (f32x4){0.f, 0.f, 0.f, 0.f};
    }

    const half_t* kbase = k_ws + ((size_t)b * NN + q) * DD + g * 8;
    const half_t* vb0 = vT_ws + ((size_t)b * DD + q) * NN + g * 4;
    const half_t* vb1 = vT_ws + ((size_t)b * DD + 16 + q) * NN + g * 4;

    const int ktbase = w * 32;

    // prologue: first iteration's K fragments
    half8_t kc0 = *reinterpret_cast<const half8_t*>(kbase + (size_t)(ktbase + 0) * 16 * DD);
    half8_t kc1 = *reinterpret_cast<const half8_t*>(kbase + (size_t)(ktbase + 1) * 16 * DD);

    for (int it = 0; it < 16; ++it) {
        const int kt = ktbase + it * 2;

        // V loads for this iteration (consumed after softmax)
        const half_t* vp0 = vb0 + (size_t)kt * 16;
        const half_t* vp1 = vb1 + (size_t)kt * 16;
        half4_t va0 = *reinterpret_cast<const half4_t*>(vp0);        // tile0, d=4g+i
        half4_t va1 = *reinterpret_cast<const half4_t*>(vp1);        // tile0, d=16+4g+i
        half4_t vc0 = *reinterpret_cast<const half4_t*>(vp0 + 16);   // tile1
        half4_t vc1 = *reinterpret_cast<const half4_t*>(vp1 + 16);

        // prefetch next iteration's K fragments
        const int ktn = (it < 15) ? (kt + 2) : kt;
        half8_t kn0 = *reinterpret_cast<const half8_t*>(kbase + (size_t)(ktn + 0) * 16 * DD);
        half8_t kn1 = *reinterpret_cast<const half8_t*>(kbase + (size_t)(ktn + 1) * 16 * DD);

        // QK^T: 8 MFMAs (4 q-tiles x 2 k-tiles) on resident K
        f32x4 z = {0.f, 0.f, 0.f, 0.f};
        f32x4 s0[4], s1[4];
#pragma unroll
        for (int t = 0; t < 4; ++t) {
            s0[t] = MFMA_QK(kc0, qf[t], z);
            s1[t] = MFMA_QK(kc1, qf[t], z);
        }

        float tmax[4];
        bool need = false;
#pragma unroll
        for (int t = 0; t < 4; ++t) {
            float t0 = fmaxf(fmaxf(s0[t][0], s0[t][1]), fmaxf(s0[t][2], s0[t][3]));
            float t1 = fmaxf(fmaxf(s1[t][0], s1[t][1]), fmaxf(s1[t][2], s1[t][3]));
            tmax[t] = fmaxf(t0, t1);
            need = need || (tmax[t] > m[t] + THR2);
        }

        // defer-max: rescale all tiles only when some lane/tile exceeds headroom
        if (__any(need)) {
#pragma unroll
            for (int t = 0; t < 4; ++t) {
                float rmax = tmax[t];
                rmax = fmaxf(rmax, __shfl_xor(rmax, 16));
                rmax = fmaxf(rmax, __shfl_xor(rmax, 32));
                float mn = fmaxf(m[t], rmax);
                float sc = fexp2(m[t] - mn);
                ssum[t] *= sc;
                accd0[t] *= sc;
                accd1[t] *= sc;
                m[t] = mn;
            }
        }

        // softmax (log2 domain) + PV for each q-tile
#pragma unroll
        for (int t = 0; t < 4; ++t) {
            float p00 = fexp2(s0[t][0] - m[t]), p01 = fexp2(s0[t][1] - m[t]);
            float p02 = fexp2(s0[t][2] - m[t]), p03 = fexp2(s0[t][3] - m[t]);
            float p10 = fexp2(s1[t][0] - m[t]), p11 = fexp2(s1[t][1] - m[t]);
            float p12 = fexp2(s1[t][2] - m[t]), p13 = fexp2(s1[t][3] - m[t]);
            ssum[t] += ((p00 + p01) + (p02 + p03)) + ((p10 + p11) + (p12 + p13));

            half4_t pf0, pf1;
            pf0[0] = (half_t)p00; pf0[1] = (half_t)p01; pf0[2] = (half_t)p02; pf0[3] = (half_t)p03;
            pf1[0] = (half_t)p10; pf1[1] = (half_t)p11; pf1[2] = (half_t)p12; pf1[3] = (half_t)p13;

            accd0[t] = MFMA_PV(va0, pf0, accd0[t]);
            accd1[t] = MFMA_PV(va1, pf0, accd1[t]);
            accd0[t] = MFMA_PV(vc0, pf1, accd0[t]);
            accd1[t] = MFMA_PV(vc1, pf1, accd1[t]);
        }

        kc0 = kn0;
        kc1 = kn1;
    }

    // fold lane-local ssum to row sums (once)
#pragma unroll
    for (int t = 0; t < 4; ++t) {
        ssum[t] += __shfl_xor(ssum[t], 16);
        ssum[t] += __shfl_xor(ssum[t], 32);
    }

    if (lane < 16) {
#pragma unroll
        for (int t = 0; t < 4; ++t) { m_l[w][t][lane] = m[t]; s_l[w][t][lane] = ssum[t]; }
    }
#pragma unroll
    for (int t = 0; t < 4; ++t)
#pragma unroll
        for (int i = 0; i < 4; ++i) {
            acc_l[w][lane][t][i] = accd0[t][i];
            acc_l[w][lane][t][4 + i] = accd1[t][i];
        }
    __syncthreads();

    // waves 0..3 combine the 8 k-splits; wave w handles q-tile t=w
    if (w < 4) {
        const int t = w;
        float M = m_l[0][t][q];
#pragma unroll
        for (int ww = 1; ww < 8; ++ww) M = fmaxf(M, m_l[ww][t][q]);
        float SS = 0.f;
        float f[8] = {0.f, 0.f, 0.f, 0.f, 0.f, 0.f, 0.f, 0.f};
#pragma unroll
        for (int ww = 0; ww < 8; ++ww) {
            float sc = fexp2(m_l[ww][t][q] - M);
            SS += s_l[ww][t][q] * sc;
#pragma unroll
            for (int i = 0; i < 8; ++i) f[i] += acc_l[ww][lane][t][i] * sc;
        }
        float inv = 1.0f / SS;
#pragma unroll
        for (int i = 0; i < 4; ++i) {
            feat_lds[t * 16 + q][g * 4 + i] = f[i] * inv;
            feat_lds[t * 16 + q][16 + g * 4 + i] = f[4 + i] * inv;
        }
    }
    __syncthreads();

    // epilogue: 64 rows x 256 cols; c = tid&255, rh = tid>>8 -> 32 rows each
    const int c = tid & 255, rh = tid >> 8;
    float wv[32];
#pragma unroll
    for (int d = 0; d < DD; ++d) wv[d] = Wo[d * CC + c];
    const float gam = gamma[0];
    const float bias = bo[c];

#pragma unroll
    for (int chunk = 0; chunk < 4; ++chunk) {
        const int r0 = rh * 32 + chunk * 8;
        float oacc[8] = {0.f, 0.f, 0.f, 0.f, 0.f, 0.f, 0.f, 0.f};
#pragma unroll
        for (int d = 0; d < DD; ++d) {
            float wvd = wv[d];
#pragma unroll
            for (int r = 0; r < 8; ++r) oacc[r] += feat_lds[r0 + r][d] * wvd;
        }
        const size_t base = ((size_t)b * NN + (size_t)q0 + r0) * CC + c;
        const float* xr = x + base;
        float* outr = out + base;
#pragma unroll
        for (int r = 0; r < 8; ++r)
            outr[(size_t)r * CC] = gam * (oacc[r] + bias) + xr[(size_t)r * CC];
    }
}

// ---------------- launch ----------------
extern "C" void kernel_launch(void* const* d_in, const int* in_sizes, int n_in,
                              void* d_out, int out_size, void* d_ws, size_t ws_size,
                              hipStream_t stream) {
    const float* x  = (const float*)d_in[0];
    const float* Wk = (const float*)d_in[1];
    const float* bk = (const float*)d_in[2];
    const float* Wq = (const float*)d_in[3];
    const float* bq = (const float*)d_in[4];
    const float* Wv = (const float*)d_in[5];
    const float* bv = (const float*)d_in[6];
    const float* Wo = (const float*)d_in[7];
    const float* bo = (const float*)d_in[8];
    const float* gamma = (const float*)d_in[9];
    float* out = (float*)d_out;

    half_t* k_ws  = (half_t*)d_ws;
    half_t* q_ws  = k_ws + (size_t)BB * NN * DD;
    half_t* vT_ws = q_ws + (size_t)BB * NN * DD;

    proj_kernel<<<1024, 192, 0, stream>>>(x, Wk, bk, Wq, bq, Wv, bv, k_ws, q_ws, vT_ws);
    attn_kernel<<<256, 512, 0, stream>>>(k_ws, q_ws, vT_ws, x, Wo, bo, gamma, out);
}

// Round 7
// 46.503 us; speedup vs baseline: 2.4108x; 1.3805x over previous
//
#include <hip/hip_runtime.h>
#include <hip/hip_bf16.h>
#include <hip/hip_fp16.h>

// Self-attention: B=4, N=4096 (64x64 spatial), C=256, D=32.
//   proj_kernel : MFMA GEMM. xf16 (LDS) @ [Wk|Wq|Wv]^T f16 (LDS) -> k,q row-major
//                 [B*N][32] (q pre-scaled by log2e); v in tiled layout
//                 vT2[b][n/16][d(32)][n%16] (1KB contiguous per 16-k tile).
//   attn_kernel : block = 64 q-rows (4 q-tiles/wave), 8 waves k-split (512 k each),
//                 swapped-operand MFMA (S^T = K*Q^T, feat^T = V^T*P^T),
//                 K and V both prefetched 1 iteration deep, defer-max softmax,
//                 then combine + output projection (feat@Wo+bo)*gamma + x.

#define BB 4
#define NN 4096
#define CC 256
#define DD 32
#define LOG2E 1.44269504088896340736f
#define THR2 11.0f

typedef _Float16 half_t;
typedef _Float16 half2_t __attribute__((ext_vector_type(2)));
typedef _Float16 half4_t __attribute__((ext_vector_type(4)));
typedef _Float16 half8_t __attribute__((ext_vector_type(8)));
typedef float f32x4 __attribute__((ext_vector_type(4)));

#define MFMA_QK(a, b, c) __builtin_amdgcn_mfma_f32_16x16x32_f16(a, b, c, 0, 0, 0)
#define MFMA_PV(a, b, c) __builtin_amdgcn_mfma_f32_16x16x16f16(a, b, c, 0, 0, 0)

static __device__ inline float fexp2(float x) {
#if __has_builtin(__builtin_amdgcn_exp2f)
    return __builtin_amdgcn_exp2f(x);
#else
    return exp2f(x);
#endif
}

// ---------------- Kernel 1: fused QKV projection (MFMA) ----------------
// grid 512 blocks x 256 threads (4 waves); block = 32 rows of x.
// Wave w: rowTile rt = w>>1 (16 rows), colTiles ct0..ct0+2 where ct0 = (w&1)*3.
// Fragment convention identical to attn's QK (validated): A/B lane&15 = row/col,
// lane>>4 selects which 8 of the 32 K-dim elements; D: col=lane&15(B), row=4g+i(A).
__global__ __launch_bounds__(256) void proj_kernel(
    const float* __restrict__ x,
    const float* __restrict__ Wk, const float* __restrict__ bk,
    const float* __restrict__ Wq, const float* __restrict__ bq,
    const float* __restrict__ Wv, const float* __restrict__ bv,
    half_t* __restrict__ k_ws, half_t* __restrict__ q_ws, half_t* __restrict__ vT2)
{
    __shared__ half_t xs16[32][264];  // x tile, f16, stride 264 (16B-aligned rows)
    __shared__ half_t Wt[96][264];    // [Wk|Wq|Wv]^T : Wt[wcol][kdim]

    const int t = threadIdx.x;
    const int row0 = blockIdx.x * 32;   // global row (never straddles batch: 32|4096)

    // stage x tile [32][256] fp32 -> f16
    const float4* x4 = reinterpret_cast<const float4*>(x) + (size_t)row0 * 64;
    for (int idx = t; idx < 32 * 64; idx += 256) {
        int r = idx >> 6, c4 = idx & 63;
        float4 v = x4[r * 64 + c4];
        half4_t h;
        h[0] = (half_t)v.x; h[1] = (half_t)v.y; h[2] = (half_t)v.z; h[3] = (half_t)v.w;
        *reinterpret_cast<half4_t*>(&xs16[r][c4 * 4]) = h;
    }

    // stage W^T (q columns pre-scaled by log2e). idx: cp fastest (conflict-free LDS).
    for (int idx = t; idx < 3072; idx += 256) {
        int cp = idx & 127;           // c-pair
        int rest = idx >> 7;          // 0..23
        int d4 = (rest & 7) * 4;
        int mat = rest >> 3;          // 0:k 1:q 2:v
        const float* Wm = (mat == 0) ? Wk : ((mat == 1) ? Wq : Wv);
        const float sc = (mat == 1) ? LOG2E : 1.0f;
        float4 w0 = *reinterpret_cast<const float4*>(Wm + (2 * cp) * DD + d4);
        float4 w1 = *reinterpret_cast<const float4*>(Wm + (2 * cp + 1) * DD + d4);
        int rbase = mat * 32 + d4;
        half2_t h;
        h[0] = (half_t)(w0.x * sc); h[1] = (half_t)(w1.x * sc);
        *reinterpret_cast<half2_t*>(&Wt[rbase + 0][2 * cp]) = h;
        h[0] = (half_t)(w0.y * sc); h[1] = (half_t)(w1.y * sc);
        *reinterpret_cast<half2_t*>(&Wt[rbase + 1][2 * cp]) = h;
        h[0] = (half_t)(w0.z * sc); h[1] = (half_t)(w1.z * sc);
        *reinterpret_cast<half2_t*>(&Wt[rbase + 2][2 * cp]) = h;
        h[0] = (half_t)(w0.w * sc); h[1] = (half_t)(w1.w * sc);
        *reinterpret_cast<half2_t*>(&Wt[rbase + 3][2 * cp]) = h;
    }
    __syncthreads();

    const int w = t >> 6, lane = t & 63;
    const int c = lane & 15, g = lane >> 4;
    const int rt = w >> 1;            // row tile 0..1
    const int ct0 = (w & 1) * 3;      // col tiles ct0..ct0+2

    f32x4 acc[3];
#pragma unroll
    for (int j = 0; j < 3; ++j) acc[j] = (f32x4){0.f, 0.f, 0.f, 0.f};

#pragma unroll
    for (int kk = 0; kk < 8; ++kk) {
        const int k0 = kk * 32 + g * 8;
        half8_t bfrag = *reinterpret_cast<const half8_t*>(&xs16[rt * 16 + c][k0]);
#pragma unroll
        for (int j = 0; j < 3; ++j) {
            half8_t afrag = *reinterpret_cast<const half8_t*>(&Wt[(ct0 + j) * 16 + c][k0]);
            acc[j] = MFMA_QK(afrag, bfrag, acc[j]);
        }
    }

    // store: lane holds C[xrow = rt*16+c][wcol = ct*16+4g+i]
    const int grow = row0 + rt * 16 + c;   // global row
#pragma unroll
    for (int j = 0; j < 3; ++j) {
        const int ct = ct0 + j;
        const int mat = ct >> 1;           // 0:k 1:q 2:v
        const float* bm = (mat == 0) ? bk : ((mat == 1) ? bq : bv);
        float4 bb = *reinterpret_cast<const float4*>(bm + (ct & 1) * 16 + g * 4);
        if (mat < 2) {
            const float bsc = (mat == 1) ? LOG2E : 1.0f;
            half_t* dst = (mat == 0) ? k_ws : q_ws;
            half4_t h;
            h[0] = (half_t)(acc[j][0] + bb.x * bsc);
            h[1] = (half_t)(acc[j][1] + bb.y * bsc);
            h[2] = (half_t)(acc[j][2] + bb.z * bsc);
            h[3] = (half_t)(acc[j][3] + bb.w * bsc);
            *reinterpret_cast<half4_t*>(dst + (size_t)grow * DD + (ct & 1) * 16 + g * 4) = h;
        } else {
            // vT2[(row0>>4)+rt][d][n%16], d = (ct&1)*16+4g+i, n%16 = c
            const size_t tbase = ((size_t)(row0 >> 4) + rt) * 512;
            const int d0 = (ct & 1) * 16 + g * 4;
            vT2[tbase + (size_t)(d0 + 0) * 16 + c] = (half_t)(acc[j][0] + bb.x);
            vT2[tbase + (size_t)(d0 + 1) * 16 + c] = (half_t)(acc[j][1] + bb.y);
            vT2[tbase + (size_t)(d0 + 2) * 16 + c] = (half_t)(acc[j][2] + bb.z);
            vT2[tbase + (size_t)(d0 + 3) * 16 + c] = (half_t)(acc[j][3] + bb.w);
        }
    }
}

// ---------------- Kernel 2: flash attention + output projection ----------------
// grid 256 blocks (b*64+qb) x 512 threads (8 waves). Block = 64 q rows (4 tiles/wave).
// Wave w: k in [w*512, (w+1)*512), 2 k-tiles of 16 per iteration, 16 iterations.
// K and V fragments prefetched one iteration deep.
__global__ __launch_bounds__(512) void attn_kernel(
    const half_t* __restrict__ k_ws, const half_t* __restrict__ q_ws,
    const half_t* __restrict__ vT2,
    const float* __restrict__ x, const float* __restrict__ Wo,
    const float* __restrict__ bo, const float* __restrict__ gamma,
    float* __restrict__ out)
{
    __shared__ float m_l[8][4][16];
    __shared__ float s_l[8][4][16];
    __shared__ float acc_l[8][64][4][8];   // 64 KB
    __shared__ float feat_lds[64][32];     // 8 KB

    const int tid = threadIdx.x;
    const int w = tid >> 6, lane = tid & 63;
    const int q = lane & 15, g = lane >> 4;
    const int b = blockIdx.x >> 6, qb = blockIdx.x & 63;
    const int q0 = qb * 64;

    // Q fragments (B-operand of S^T = K*Q^T), pre-scaled by log2e
    half8_t qf[4];
#pragma unroll
    for (int t = 0; t < 4; ++t)
        qf[t] = *reinterpret_cast<const half8_t*>(
            q_ws + (size_t)(b * NN + q0 + t * 16 + q) * DD + g * 8);

    float m[4], ssum[4];
    f32x4 accd0[4], accd1[4];
#pragma unroll
    for (int t = 0; t < 4; ++t) {
        m[t] = -3.0e38f; ssum[t] = 0.f;
        accd0[t] = (f32x4){0.f, 0.f, 0.f, 0.f};
        accd1[t] = (f32x4){0.f, 0.f, 0.f, 0.f};
    }

    const half_t* kbase = k_ws + ((size_t)b * NN + q) * DD + g * 8;
    // vT2: per-16-k tile of 512 halves: [d(32)][n%16]; lane reads d={q,16+q}, j=g*4+i
    const half_t* vb = vT2 + (size_t)b * 256 * 512 + q * 16 + g * 4;

    const int ktbase = w * 32;

    // prologue: iteration 0's K and V fragments
    half8_t kc0 = *reinterpret_cast<const half8_t*>(kbase + (size_t)(ktbase + 0) * 16 * DD);
    half8_t kc1 = *reinterpret_cast<const half8_t*>(kbase + (size_t)(ktbase + 1) * 16 * DD);
    half4_t va0 = *reinterpret_cast<const half4_t*>(vb + (size_t)(ktbase + 0) * 512);
    half4_t va1 = *reinterpret_cast<const half4_t*>(vb + (size_t)(ktbase + 0) * 512 + 256);
    half4_t vc0 = *reinterpret_cast<const half4_t*>(vb + (size_t)(ktbase + 1) * 512);
    half4_t vc1 = *reinterpret_cast<const half4_t*>(vb + (size_t)(ktbase + 1) * 512 + 256);

    for (int it = 0; it < 16; ++it) {
        const int kt = ktbase + it * 2;
        const int ktn = (it < 15) ? (kt + 2) : kt;

        // prefetch next iteration's K and V fragments
        half8_t kn0 = *reinterpret_cast<const half8_t*>(kbase + (size_t)(ktn + 0) * 16 * DD);
        half8_t kn1 = *reinterpret_cast<const half8_t*>(kbase + (size_t)(ktn + 1) * 16 * DD);
        half4_t wa0 = *reinterpret_cast<const half4_t*>(vb + (size_t)(ktn + 0) * 512);
        half4_t wa1 = *reinterpret_cast<const half4_t*>(vb + (size_t)(ktn + 0) * 512 + 256);
        half4_t wc0 = *reinterpret_cast<const half4_t*>(vb + (size_t)(ktn + 1) * 512);
        half4_t wc1 = *reinterpret_cast<const half4_t*>(vb + (size_t)(ktn + 1) * 512 + 256);

        // QK^T: 8 MFMAs (4 q-tiles x 2 k-tiles) on resident K
        f32x4 z = {0.f, 0.f, 0.f, 0.f};
        f32x4 s0[4], s1[4];
#pragma unroll
        for (int t = 0; t < 4; ++t) {
            s0[t] = MFMA_QK(kc0, qf[t], z);
            s1[t] = MFMA_QK(kc1, qf[t], z);
        }

        float tmax[4];
        bool need = false;
#pragma unroll
        for (int t = 0; t < 4; ++t) {
            float t0 = fmaxf(fmaxf(s0[t][0], s0[t][1]), fmaxf(s0[t][2], s0[t][3]));
            float t1 = fmaxf(fmaxf(s1[t][0], s1[t][1]), fmaxf(s1[t][2], s1[t][3]));
            tmax[t] = fmaxf(t0, t1);
            need = need || (tmax[t] > m[t] + THR2);
        }

        // defer-max: rescale only when some lane/tile exceeds headroom
        if (__any(need)) {
#pragma unroll
            for (int t = 0; t < 4; ++t) {
                float rmax = tmax[t];
                rmax = fmaxf(rmax, __shfl_xor(rmax, 16));
                rmax = fmaxf(rmax, __shfl_xor(rmax, 32));
                float mn = fmaxf(m[t], rmax);
                float sc = fexp2(m[t] - mn);
                ssum[t] *= sc;
                accd0[t] *= sc;
                accd1[t] *= sc;
                m[t] = mn;
            }
        }

        // softmax (log2 domain) + PV for each q-tile
#pragma unroll
        for (int t = 0; t < 4; ++t) {
            float p00 = fexp2(s0[t][0] - m[t]), p01 = fexp2(s0[t][1] - m[t]);
            float p02 = fexp2(s0[t][2] - m[t]), p03 = fexp2(s0[t][3] - m[t]);
            float p10 = fexp2(s1[t][0] - m[t]), p11 = fexp2(s1[t][1] - m[t]);
            float p12 = fexp2(s1[t][2] - m[t]), p13 = fexp2(s1[t][3] - m[t]);
            ssum[t] += ((p00 + p01) + (p02 + p03)) + ((p10 + p11) + (p12 + p13));

            half4_t pf0, pf1;
            pf0[0] = (half_t)p00; pf0[1] = (half_t)p01; pf0[2] = (half_t)p02; pf0[3] = (half_t)p03;
            pf1[0] = (half_t)p10; pf1[1] = (half_t)p11; pf1[2] = (half_t)p12; pf1[3] = (half_t)p13;

            accd0[t] = MFMA_PV(va0, pf0, accd0[t]);
            accd1[t] = MFMA_PV(va1, pf0, accd1[t]);
            accd0[t] = MFMA_PV(vc0, pf1, accd0[t]);
            accd1[t] = MFMA_PV(vc1, pf1, accd1[t]);
        }

        kc0 = kn0; kc1 = kn1;
        va0 = wa0; va1 = wa1; vc0 = wc0; vc1 = wc1;
    }

    // fold lane-local ssum to row sums (once)
#pragma unroll
    for (int t = 0; t < 4; ++t) {
        ssum[t] += __shfl_xor(ssum[t], 16);
        ssum[t] += __shfl_xor(ssum[t], 32);
    }

    if (lane < 16) {
#pragma unroll
        for (int t = 0; t < 4; ++t) { m_l[w][t][lane] = m[t]; s_l[w][t][lane] = ssum[t]; }
    }
#pragma unroll
    for (int t = 0; t < 4; ++t)
#pragma unroll
        for (int i = 0; i < 4; ++i) {
            acc_l[w][lane][t][i] = accd0[t][i];
            acc_l[w][lane][t][4 + i] = accd1[t][i];
        }
    __syncthreads();

    // waves 0..3 combine the 8 k-splits; wave w handles q-tile t=w
    if (w < 4) {
        const int t = w;
        float M = m_l[0][t][q];
#pragma unroll
        for (int ww = 1; ww < 8; ++ww) M = fmaxf(M, m_l[ww][t][q]);
        float SS = 0.f;
        float f[8] = {0.f, 0.f, 0.f, 0.f, 0.f, 0.f, 0.f, 0.f};
#pragma unroll
        for (int ww = 0; ww < 8; ++ww) {
            float sc = fexp2(m_l[ww][t][q] - M);
            SS += s_l[ww][t][q] * sc;
#pragma unroll
            for (int i = 0; i < 8; ++i) f[i] += acc_l[ww][lane][t][i] * sc;
        }
        float inv = 1.0f / SS;
#pragma unroll
        for (int i = 0; i < 4; ++i) {
            feat_lds[t * 16 + q][g * 4 + i] = f[i] * inv;
            feat_lds[t * 16 + q][16 + g * 4 + i] = f[4 + i] * inv;
        }
    }
    __syncthreads();

    // epilogue: 64 rows x 256 cols; c = tid&255, rh = tid>>8 -> 32 rows each
    const int c = tid & 255, rh = tid >> 8;
    float wv[32];
#pragma unroll
    for (int d = 0; d < DD; ++d) wv[d] = Wo[d * CC + c];
    const float gam = gamma[0];
    const float bias = bo[c];

#pragma unroll
    for (int chunk = 0; chunk < 4; ++chunk) {
        const int r0 = rh * 32 + chunk * 8;
        float oacc[8] = {0.f, 0.f, 0.f, 0.f, 0.f, 0.f, 0.f, 0.f};
#pragma unroll
        for (int d = 0; d < DD; ++d) {
            float wvd = wv[d];
#pragma unroll
            for (int r = 0; r < 8; ++r) oacc[r] += feat_lds[r0 + r][d] * wvd;
        }
        const size_t base = ((size_t)b * NN + (size_t)q0 + r0) * CC + c;
        const float* xr = x + base;
        float* outr = out + base;
#pragma unroll
        for (int r = 0; r < 8; ++r)
            outr[(size_t)r * CC] = gam * (oacc[r] + bias) + xr[(size_t)r * CC];
    }
}

// ---------------- launch ----------------
extern "C" void kernel_launch(void* const* d_in, const int* in_sizes, int n_in,
                              void* d_out, int out_size, void* d_ws, size_t ws_size,
                              hipStream_t stream) {
    const float* x  = (const float*)d_in[0];
    const float* Wk = (const float*)d_in[1];
    const float* bk = (const float*)d_in[2];
    const float* Wq = (const float*)d_in[3];
    const float* bq = (const float*)d_in[4];
    const float* Wv = (const float*)d_in[5];
    const float* bv = (const float*)d_in[6];
    const float* Wo = (const float*)d_in[7];
    const float* bo = (const float*)d_in[8];
    const float* gamma = (const float*)d_in[9];
    float* out = (float*)d_out;

    half_t* k_ws  = (half_t*)d_ws;
    half_t* q_ws  = k_ws + (size_t)BB * NN * DD;
    half_t* vT2   = q_ws + (size_t)BB * NN * DD;

    proj_kernel<<<512, 256, 0, stream>>>(x, Wk, bk, Wq, bq, Wv, bv, k_ws, q_ws, vT2);
    attn_kernel<<<256, 512, 0, stream>>>(k_ws, q_ws, vT2, x, Wo, bo, gamma, out);
}